// Round 13
// baseline (233.913 us; speedup 1.0000x reference)
//
#include <hip/hip_runtime.h>
#include <hip/hip_bf16.h>
#include <cstdint>
#include <cstddef>

// Masked causal dense attention, B=8, Tq=Tv=2048, D=512, key==value.
// R13 = R5's verified 32x32x16 datapath (k-split pair QK + sS combine +
// in-register P via cvt_pkrtz/shfl_xor(32) + 80B-padded sVT) x R12's verified
// pipeline (waves_per_eu(2,2) no-spill, double-buffered sV, counted vmcnt,
// LDS mask table, NS-split LPT schedule). sV swizzle FIXED to full (v&7)
// chunk-XOR (R12's <<2 variant spread reads over 2/8 bank groups = 4x floor).
// Block: 512 thr, 8 waves = 4 pairs; pair p owns q-tile 4G+p (32 rows);
// kslice=w&1 splits K for QK and D for PV. 2x FLOP/LDS-byte, half the
// iterations of R12 (128 q-rows per staged KV tile).

#define TQ   2048
#define TV   2048
#define DIM  512
#define NB   8
#define NROW (NB * TQ)
#define NSLOT 57   // sum over G=0..15 of NS(G), NS(G) = ceil((4G+4)/11)

typedef _Float16 f16x8 __attribute__((ext_vector_type(8)));
typedef _Float16 f16x4 __attribute__((ext_vector_type(4)));
typedef float    f32x4  __attribute__((ext_vector_type(4)));
typedef float    f32x16 __attribute__((ext_vector_type(16)));
typedef int      i32x4  __attribute__((ext_vector_type(4)));

__device__ __forceinline__ int sched_ns(int G) { return (4 * G + 14) / 11; }

// ---- mask dtype runtime detection (bool may arrive as u8 / i32 / i64 / f32) ----
__device__ __forceinline__ int mask_fmt(const void* qm) {
    const unsigned* p = (const unsigned*)qm;
    unsigned w0 = p[0];
    if (w0 & 0xFF00u) return 0;                  // u8
    unsigned w1 = p[1];
    if (w0 == 1u) return (w1 != 0u) ? 1 : 2;     // i32 vs i64
    return 3;                                     // f32
}
__device__ __forceinline__ bool mask_bit(const void* m, int fmt, size_t i) {
    if (fmt == 0) return ((const unsigned char*)m)[i] != 0;
    if (fmt == 1) return ((const int*)m)[i] != 0;
    if (fmt == 2) return ((const unsigned*)m)[2 * i] != 0;
    return ((const float*)m)[i] != 0.0f;
}

// global -> LDS DMA, 16B per lane; LDS dest = uniform base + lane*16 (linear)
__device__ __forceinline__ void gload_lds16(const void* g, void* l) {
    __builtin_amdgcn_global_load_lds(
        (const __attribute__((address_space(1))) unsigned int*)g,
        (__attribute__((address_space(3))) unsigned int*)l, 16, 0, 0);
}

__global__ void cvt_f16_kernel(const float* __restrict__ in, _Float16* __restrict__ out, int n8) {
    int i = blockIdx.x * blockDim.x + threadIdx.x;
    if (i >= n8) return;
    f32x4 x0 = *(const f32x4*)(in + (size_t)i * 8);
    f32x4 x1 = *(const f32x4*)(in + (size_t)i * 8 + 4);
    f16x8 o;
#pragma unroll
    for (int j = 0; j < 4; ++j) { o[j] = (_Float16)x0[j]; o[4 + j] = (_Float16)x1[j]; }
    *(f16x8*)(out + (size_t)i * 8) = o;
}

// ---- V f32 -> wv f16 row-major + wvt f16 transposed [b][d][v] (64x64 LDS tiles) ----
__global__ __launch_bounds__(256)
void prep_v_kernel(const float* __restrict__ vf, _Float16* __restrict__ wv,
                   _Float16* __restrict__ wvt) {
    __shared__ float sT[64][65];
    int z   = blockIdx.x;
    int b   = z & 7;
    int tv0 = ((z >> 3) & 31) * 64;
    int d0  = (z >> 8) * 64;
    int tid = threadIdx.x;
    int vl  = tid >> 4;
    int dq  = (tid & 15) * 4;
#pragma unroll
    for (int i = 0; i < 4; ++i) {
        int v = vl + i * 16;
        f32x4 x = *(const f32x4*)(vf + ((size_t)b * TV + tv0 + v) * DIM + d0 + dq);
        f16x4 h;
#pragma unroll
        for (int j = 0; j < 4; ++j) { h[j] = (_Float16)x[j]; sT[v][dq + j] = x[j]; }
        *(f16x4*)(wv + ((size_t)b * TV + tv0 + v) * DIM + d0 + dq) = h;
    }
    __syncthreads();
    int dl = tid >> 4;           // 0..15
    int vq = (tid & 15) * 4;     // 0..60
#pragma unroll
    for (int i = 0; i < 4; ++i) {
        int dloc = dl + i * 16;
        f16x4 h;
#pragma unroll
        for (int j = 0; j < 4; ++j) h[j] = (_Float16)sT[vq + j][dloc];
        *(f16x4*)(wvt + ((size_t)b * DIM + d0 + dloc) * TV + tv0 + vq) = h;
    }
}

__global__ __launch_bounds__(512)
__attribute__((amdgpu_waves_per_eu(2, 2)))
void attn_kernel(const _Float16* __restrict__ wq, const _Float16* __restrict__ wv,
                 const _Float16* __restrict__ wvt,
                 const void* __restrict__ qmask, const void* __restrict__ vmask,
                 _Float16* __restrict__ pacc, float* __restrict__ pml) {
    // 136.25 KB LDS -> 1 block/CU (8 waves = 2/SIMD, matching waves_per_eu(2,2)).
    __shared__ __align__(16) _Float16 sV[2][32 * 512];  // [32 v][512 k]; chunk c at c^(v&7)
    __shared__ __align__(16) char     sVT[512 * 80];    // [512 d] x 80B rows (64B data+16B pad)
    __shared__ float sS[8 * 1024];                      // per-wave 32x32 f32 S-partials
    __shared__ unsigned sMW[64];                        // per-KV-tile v_mask words

    const int tid  = threadIdx.x;
    const int lane = tid & 63;
    const int w    = tid >> 6;        // wave 0..7
    const int l31  = lane & 31;
    const int h    = lane >> 5;       // half-wave

    const int bid  = blockIdx.x;
    const int b    = bid & 7;                    // batch -> XCD L2 locality
    const int slot = (NSLOT - 1) - (bid >> 3);   // LPT: longest (large G) first

    // slot -> (G, s)
    int G = 0, s = 0;
    {
        int base = 0;
#pragma unroll
        for (int j = 0; j < 16; ++j) {
            int n = sched_ns(j);
            if (slot >= base && slot < base + n) { G = j; s = slot - base; }
            base += n;
        }
    }
    const int NSg = sched_ns(G);

    const int p      = w >> 1;            // pair 0..3 -> q-tile 4G+p (32 rows)
    const int kslice = w & 1;             // QK K-half / PV d-half
    const int qtile  = 4 * G + p;
    const int qrow   = qtile * 32 + l31;
    const size_t qrowG = (size_t)b * TQ + qrow;
    const int bound = qtile;              // causal: KV tiles t <= qtile

    const int fmt = mask_fmt(qmask);

    // q activity: 2 ballots cover the block's 128 rows
    unsigned long long bal0 = __ballot(mask_bit(qmask, fmt, (size_t)b * TQ + G * 128 + lane));
    unsigned long long bal1 = __ballot(mask_bit(qmask, fmt, (size_t)b * TQ + G * 128 + 64 + lane));
    bool pact0 = (bal0 & 0xFFFFFFFFull) != 0ull;
    bool pact1 = (bal0 >> 32) != 0ull;
    bool pact2 = (bal1 & 0xFFFFFFFFull) != 0ull;
    bool pact3 = (bal1 >> 32) != 0ull;
    const bool waveActive = (p == 0) ? pact0 : (p == 1) ? pact1 : (p == 2) ? pact2 : pact3;
    int bmaxb = -1;
    if (pact0) bmaxb = 4 * G;
    if (pact1) bmaxb = 4 * G + 1;
    if (pact2) bmaxb = 4 * G + 2;
    if (pact3) bmaxb = 4 * G + 3;

    // v_mask table (wave 0 fills via ballots; visible after prologue barrier)
    if (w == 0) {
#pragma unroll
        for (int c = 0; c < 32; ++c) {
            unsigned long long bal = __ballot(mask_bit(vmask, fmt, (size_t)b * TV + c * 64 + lane));
            if (lane == 0) {
                sMW[2 * c]     = (unsigned)(bal & 0xFFFFFFFFull);
                sMW[2 * c + 1] = (unsigned)(bal >> 32);
            }
        }
    }

    // ---- Q B-frags: lane holds Q[qrow][kslice*256 + kst*16 + h*8 + j] (64 VGPR) ----
    f16x8 qreg[16];
    if (waveActive) {
#pragma unroll
        for (int kst = 0; kst < 16; ++kst)
            qreg[kst] = *(const f16x8*)(wq + qrowG * DIM + kslice * 256 + kst * 16 + h * 8);
    }

    // ---- staging ----
    auto stage_sV = [&](int buf, int tt) {   // 4 DMA/wave; source pre-swizzled chunk^(v&7)
#pragma unroll
        for (int k = 0; k < 4; ++k) {
            int vr = w * 4 + k;
            const _Float16* src = wv + ((size_t)b * TV + tt * 32 + vr) * DIM
                                     + ((lane ^ (vr & 7)) << 3);
            gload_lds16(src, (char*)&sV[buf][0] + vr * 1024);
        }
    };
    auto stage_sVT = [&](int tt) {           // 5 DMA/wave; 80B rows, linear dest
#pragma unroll
        for (int k = 0; k < 5; ++k) {
            int slot2 = k * 64 + lane;       // 0..319
            int dloc  = slot2 / 5;           // 0..63 within wave's 64 d-rows
            int c     = slot2 - dloc * 5;
            int cs    = (c >= 4) ? 0 : c;    // pad slot loads a valid chunk (dummy)
            const _Float16* src = wvt + ((size_t)b * DIM + w * 64 + dloc) * TV + tt * 32 + cs * 8;
            gload_lds16(src, sVT + w * 5120 + k * 1024);
        }
    };

    f32x16 acc[8];   // out^T[dhalf*256 + dt*32 + rowfn(r,h)][q=l31]
#pragma unroll
    for (int dt = 0; dt < 8; ++dt) acc[dt] = (f32x16)(0.f);
    float m_run = -3.0e38f, l_run = 0.0f;

    if (bmaxb >= s) {
        stage_sV(0, s);
        int t1 = s + NSg; if (t1 > bmaxb) t1 = bmaxb;
        stage_sV(1, t1);
        asm volatile("s_waitcnt vmcnt(4) lgkmcnt(0)" ::: "memory");  // buf0 + sMW ready
        __builtin_amdgcn_s_barrier();

        int cur = 0;
        for (int t = s; t <= bmaxb; t += NSg) {
            const int vb = t * 32;
            const unsigned mw = sMW[t];            // uniform LDS broadcast, no VMEM
            if (mw == 0u) break;                   // monotone length mask; uniform
            const bool act = waveActive && (t <= bound);
            const _Float16* sVc = &sV[cur][0];

            stage_sVT(t);                          // +5 in flight (needed only at PV)

            // === QK: S^T-partial = V[.,kslice] x Q^T[kslice,.] (16 MFMA 32x32x16) ===
            f32x16 S = (f32x16)(0.f);
            if (act) {
                __builtin_amdgcn_s_setprio(1);
#pragma unroll
                for (int kst = 0; kst < 16; ++kst) {
                    int cw = kslice * 32 + kst * 2 + h;
                    f16x8 a = *(const f16x8*)((const char*)sVc + l31 * 1024
                                              + ((cw ^ (l31 & 7)) << 4));
                    S = __builtin_amdgcn_mfma_f32_32x32x16_f16(a, qreg[kst], S, 0, 0, 0);
                }
                __builtin_amdgcn_s_setprio(0);
#pragma unroll
                for (int r = 0; r < 16; ++r) {
                    int vl = (r & 3) + 8 * (r >> 2) + 4 * h;
                    sS[w * 1024 + vl * 32 + l31] = S[r];   // 2 lanes/bank = free
                }
            }
            asm volatile("s_waitcnt lgkmcnt(0)" ::: "memory");
            __builtin_amdgcn_s_barrier();          // B1: sV reads + S-partials done
            int t2 = t + 2 * NSg; if (t2 > bmaxb) t2 = bmaxb;
            stage_sV(cur, t2);                     // +4 (freed buffer)

            f16x8 fragA, fragB;
            if (act) {
                // combine partner partial -> full S; mask; online softmax (T13 defer-max)
                float tm = -3.0e38f;
#pragma unroll
                for (int r = 0; r < 16; ++r) {
                    int vl = (r & 3) + 8 * (r >> 2) + 4 * h;
                    float x = S[r] + sS[(w ^ 1) * 1024 + vl * 32 + l31];
                    bool valid = ((vb + vl) <= qrow) && ((mw >> vl) & 1u);
                    x = valid ? x : (x - 1e9f);
                    S[r] = x;
                    tm = fmaxf(tm, x);
                }
                tm = fmaxf(tm, __shfl_xor(tm, 32, 64));
                if (!__all(tm <= m_run + 8.0f)) {
                    float mn = fmaxf(m_run, tm);
                    float rr = __expf(m_run - mn);
                    l_run *= rr;
#pragma unroll
                    for (int dt = 0; dt < 8; ++dt) acc[dt] *= rr;
                    m_run = mn;
                }
                float ps = 0.0f;
#pragma unroll
                for (int r = 0; r < 16; ++r) { S[r] = __expf(S[r] - m_run); ps += S[r]; }
                ps += __shfl_xor(ps, 32, 64);
                l_run += ps;

                // P -> B-frags in-register (R5-verified): pk pairs + cross-half shfl
                int pk0 = __builtin_bit_cast(int, __builtin_amdgcn_cvt_pkrtz(S[0],  S[1]));
                int pk1 = __builtin_bit_cast(int, __builtin_amdgcn_cvt_pkrtz(S[2],  S[3]));
                int pk2 = __builtin_bit_cast(int, __builtin_amdgcn_cvt_pkrtz(S[4],  S[5]));
                int pk3 = __builtin_bit_cast(int, __builtin_amdgcn_cvt_pkrtz(S[6],  S[7]));
                int pk4 = __builtin_bit_cast(int, __builtin_amdgcn_cvt_pkrtz(S[8],  S[9]));
                int pk5 = __builtin_bit_cast(int, __builtin_amdgcn_cvt_pkrtz(S[10], S[11]));
                int pk6 = __builtin_bit_cast(int, __builtin_amdgcn_cvt_pkrtz(S[12], S[13]));
                int pk7 = __builtin_bit_cast(int, __builtin_amdgcn_cvt_pkrtz(S[14], S[15]));
                int x0 = __shfl_xor(pk0, 32, 64), x1 = __shfl_xor(pk1, 32, 64);
                int x2 = __shfl_xor(pk2, 32, 64), x3 = __shfl_xor(pk3, 32, 64);
                int x4 = __shfl_xor(pk4, 32, 64), x5 = __shfl_xor(pk5, 32, 64);
                int x6 = __shfl_xor(pk6, 32, 64), x7 = __shfl_xor(pk7, 32, 64);
                i32x4 fa, fb;
                fa[0] = h ? x2 : pk0;  fa[1] = h ? x3 : pk1;
                fa[2] = h ? pk2 : x0;  fa[3] = h ? pk3 : x1;
                fb[0] = h ? x6 : pk4;  fb[1] = h ? x7 : pk5;
                fb[2] = h ? pk6 : x4;  fb[3] = h ? pk7 : x5;
                fragA = __builtin_bit_cast(f16x8, fa);
                fragB = __builtin_bit_cast(f16x8, fb);
            }
            asm volatile("s_waitcnt vmcnt(4)" ::: "memory");   // sVT(t) landed (own 5)
            __builtin_amdgcn_s_barrier();                      // B2: sVT ready block-wide

            // === PV: out^T[d][q] += VT x P^T over this wave's 256-d half ===
            if (act) {
                __builtin_amdgcn_s_setprio(1);
#pragma unroll
                for (int dt = 0; dt < 8; ++dt) {
                    const char* rowp = sVT + (kslice * 256 + dt * 32 + l31) * 80;
                    f16x8 a0 = *(const f16x8*)(rowp + h * 16);
                    acc[dt] = __builtin_amdgcn_mfma_f32_32x32x16_f16(a0, fragA, acc[dt], 0, 0, 0);
                    f16x8 a1 = *(const f16x8*)(rowp + 32 + h * 16);
                    acc[dt] = __builtin_amdgcn_mfma_f32_32x32x16_f16(a1, fragB, acc[dt], 0, 0, 0);
                }
                __builtin_amdgcn_s_setprio(0);
            }
            __builtin_amdgcn_s_barrier();                      // B3: sVT reads done
            cur ^= 1;
        }
    }
    asm volatile("s_waitcnt vmcnt(0) lgkmcnt(0)" ::: "memory");

    // ---- epilogue: normalized f16 partials + (m,l) (R5-verified layout) ----
    float inv = (l_run > 0.f) ? (1.0f / l_run) : 0.0f;
    _Float16* pb = pacc + (((size_t)(b * NSLOT + slot) * 128) + p * 32 + l31) * DIM;
#pragma unroll
    for (int dt = 0; dt < 8; ++dt) {
#pragma unroll
        for (int gb = 0; gb < 4; ++gb) {
            f16x4 hh;
#pragma unroll
            for (int j = 0; j < 4; ++j) hh[j] = (_Float16)(acc[dt][gb * 4 + j] * inv);
            int d = kslice * 256 + dt * 32 + gb * 8 + 4 * h;
            *(f16x4*)(pb + d) = hh;
        }
    }
    if (kslice == 0 && h == 0) {
        size_t mi = (((size_t)(b * NSLOT + slot) * 128) + p * 32 + l31) * 2;
        pml[mi]     = m_run;
        pml[mi + 1] = l_run;
    }
}

__global__ __launch_bounds__(256)
void combine_kernel(const _Float16* __restrict__ pacc, const float* __restrict__ pml,
                    const void* __restrict__ qmask, float* __restrict__ out) {
    int gid = blockIdx.x * 256 + threadIdx.x;
    int row = gid >> 7;
    int c   = (gid & 127) * 4;
    if (row >= NROW) return;
    int b      = row >> 11;
    int local  = row & 2047;
    int g      = local >> 7;          // 128 rows per group
    int rowInG = local & 127;
    int ns     = sched_ns(g);
    int st     = 0;
    for (int j = 0; j < 16; ++j) if (j < g) st += sched_ns(j);

    float m = -3.0e38f;
    for (int s2 = 0; s2 < ns; ++s2) {
        size_t idx = ((size_t)(b * NSLOT + st + s2) * 128) + rowInG;
        float l2 = pml[idx * 2 + 1];
        if (l2 > 0.f) m = fmaxf(m, pml[idx * 2]);
    }
    float L = 0.f;
    f32x4 o = (f32x4){0.f, 0.f, 0.f, 0.f};
    for (int s2 = 0; s2 < ns; ++s2) {
        size_t idx = ((size_t)(b * NSLOT + st + s2) * 128) + rowInG;
        float l2 = pml[idx * 2 + 1];
        if (l2 > 0.f) {
            float wgt = __expf(pml[idx * 2] - m) * l2;
            L += wgt;
            f16x4 hh = *(const f16x4*)(pacc + idx * DIM + c);
#pragma unroll
            for (int j = 0; j < 4; ++j) o[j] += wgt * (float)hh[j];
        }
    }
    int fmt = mask_fmt(qmask);
    bool qb = mask_bit(qmask, fmt, (size_t)row);
    float invL = (L > 0.f && qb) ? (1.0f / L) : 0.f;
    o *= invL;
    *(f32x4*)(out + (size_t)row * DIM + c) = o;
}

extern "C" void kernel_launch(void* const* d_in, const int* in_sizes, int n_in,
                              void* d_out, int out_size, void* d_ws, size_t ws_size,
                              hipStream_t stream) {
    const float* q = (const float*)d_in[0];
    const float* v = (const float*)d_in[1];
    const void* qm = d_in[2];
    const void* vm = d_in[3];
    float* out = (float*)d_out;

    const size_t nElem = (size_t)NB * TQ * DIM;                    // 8,388,608
    const size_t wqB   = nElem * sizeof(_Float16);                 // 16.78 MB
    const size_t wvB   = wqB, wvtB = wqB;
    const size_t paccB = (size_t)NB * NSLOT * 128 * DIM * sizeof(_Float16);  // 59.8 MB
    const size_t pmlB  = (size_t)NB * NSLOT * 128 * 2 * sizeof(float);       // 0.47 MB

    if (ws_size < wqB + wvB + wvtB + paccB + pmlB) {   // ~110.6 MB; R7 proved >=116 available
        (void)hipMemsetAsync(d_out, 0, (size_t)out_size * sizeof(float), stream);
        return;
    }
    _Float16* wq   = (_Float16*)d_ws;
    _Float16* wv   = (_Float16*)((char*)d_ws + wqB);
    _Float16* wvt  = (_Float16*)((char*)d_ws + wqB + wvB);
    _Float16* pacc = (_Float16*)((char*)d_ws + wqB + wvB + wvtB);
    float*    pml  = (float*)((char*)d_ws + wqB + wvB + wvtB + paccB);

    int n8 = (int)(nElem / 8);
    cvt_f16_kernel<<<dim3(n8 / 256), dim3(256), 0, stream>>>(q, wq, n8);
    prep_v_kernel<<<dim3(2048), dim3(256), 0, stream>>>(v, wv, wvt);
    attn_kernel<<<dim3(NB * NSLOT), dim3(512), 0, stream>>>(wq, wv, wvt, qm, vm, pacc, pml);
    combine_kernel<<<dim3(NROW * 128 / 256), dim3(256), 0, stream>>>(pacc, pml, qm, out);
}